// Round 1
// baseline (1152.230 us; speedup 1.0000x reference)
//
#include <hip/hip_runtime.h>

#define N_NODESC 50000
#define N_EDGESC 400000
#define N_GRAPHSC 128
#define IN_DIMC 768
#define HIDC 128
#define NCLSC 11
#define BN_EPSC 1e-5f

typedef __bf16 bf16_t;
typedef __bf16 bf16x4 __attribute__((ext_vector_type(4)));
typedef __bf16 bf16x8 __attribute__((ext_vector_type(8)));
typedef float f32x4 __attribute__((ext_vector_type(4)));

__device__ inline f32x4 mfma_16x16x32_bf16(bf16x8 a, bf16x8 b, f32x4 c) {
    return __builtin_amdgcn_mfma_f32_16x16x32_bf16(a, b, c, 0, 0, 0);
}

// C[M,256] = A[M,K] @ [Bl;Br]^T.  A row-major (fp32 or bf16), Bl/Br [128,K] fp32 row-major.
// blockIdx.y selects Bl (cols 0..127) or Br (cols 128..255).
// 256 threads = 4 waves in 2x2; each wave computes a 64x64 sub-tile as 4x4 MFMA tiles.
template<bool A_IS_F32>
__global__ __launch_bounds__(256) void gemm_kernel(const void* __restrict__ Av,
                                                   const float* __restrict__ Bl,
                                                   const float* __restrict__ Br,
                                                   float* __restrict__ C, int M, int K)
{
    __shared__ bf16_t As[128][40];   // pad 32->40 (80B stride): 16B-aligned b128 reads, 2-way banks (free)
    __shared__ bf16_t Bs[128][40];

    const int t  = threadIdx.x;
    const int m0 = blockIdx.x * 128;
    const int n0 = blockIdx.y * 128;
    const float* Bsel = (blockIdx.y == 0) ? Bl : Br;

    const int r  = t >> 3;         // staging row 0..31 (+p*32)
    const int c4 = (t & 7) * 4;    // staging col 0,4,...,28

    const int wid  = t >> 6;
    const int lane = t & 63;
    const int wm   = (wid >> 1) * 64;
    const int wn   = (wid & 1) * 64;
    const int l16  = lane & 15;
    const int quad = lane >> 4;

    f32x4 acc[4][4] = {};

    for (int k0 = 0; k0 < K; k0 += 32) {
#pragma unroll
        for (int p = 0; p < 4; p++) {
            int row = r + p * 32;
            int am  = m0 + row; if (am > M - 1) am = M - 1;   // clamp (garbage rows never stored)
            if (A_IS_F32) {
                const float* A = (const float*)Av;
                float4 v = *(const float4*)&A[(size_t)am * K + k0 + c4];
                As[row][c4 + 0] = (bf16_t)v.x; As[row][c4 + 1] = (bf16_t)v.y;
                As[row][c4 + 2] = (bf16_t)v.z; As[row][c4 + 3] = (bf16_t)v.w;
            } else {
                const bf16_t* A = (const bf16_t*)Av;
                bf16x4 v = *(const bf16x4*)&A[(size_t)am * K + k0 + c4];
                *(bf16x4*)&As[row][c4] = v;
            }
            float4 w = *(const float4*)&Bsel[(size_t)row * K + k0 + c4];
            Bs[row][c4 + 0] = (bf16_t)w.x; Bs[row][c4 + 1] = (bf16_t)w.y;
            Bs[row][c4 + 2] = (bf16_t)w.z; Bs[row][c4 + 3] = (bf16_t)w.w;
        }
        __syncthreads();

        bf16x8 af[4], bfr[4];
#pragma unroll
        for (int i = 0; i < 4; i++)
            af[i] = *(const bf16x8*)&As[wm + i * 16 + l16][quad * 8];
#pragma unroll
        for (int j = 0; j < 4; j++)
            bfr[j] = *(const bf16x8*)&Bs[wn + j * 16 + l16][quad * 8];
#pragma unroll
        for (int i = 0; i < 4; i++)
#pragma unroll
            for (int j = 0; j < 4; j++)
                acc[i][j] = mfma_16x16x32_bf16(af[i], bfr[j], acc[i][j]);
        __syncthreads();
    }

    // C/D layout (m89-verified): col = lane&15, row = quad*4 + reg
#pragma unroll
    for (int i = 0; i < 4; i++) {
        int rowb = m0 + wm + i * 16 + quad * 4;
#pragma unroll
        for (int j = 0; j < 4; j++) {
            int col = n0 + wn + j * 16 + l16;
#pragma unroll
            for (int rr = 0; rr < 4; rr++) {
                int row = rowb + rr;
                if (row < M) C[(size_t)row * 256 + col] = acc[i][j][rr];
            }
        }
    }
}

__global__ void deg_kernel(const int* __restrict__ ei, float* __restrict__ deg) {
    int e = blockIdx.x * blockDim.x + threadIdx.x;
    if (e < N_EDGESC) atomicAdd(&deg[ei[N_EDGESC + e]], 1.0f);
}

// AGG[dst,c] += P[src, c]  (Pl = first 128 cols of P)
__global__ void scatter_kernel(const int* __restrict__ ei, const float* __restrict__ P,
                               float* __restrict__ AGG) {
    int idx = blockIdx.x * blockDim.x + threadIdx.x;   // e*128 + c, max 51.2M < 2^31
    if (idx >= N_EDGESC * HIDC) return;
    int e = idx >> 7;
    int c = idx & 127;
    int s = ei[e];
    int d = ei[N_EDGESC + e];
    atomicAdd(&AGG[(size_t)d * HIDC + c], P[(size_t)s * 256 + c]);
}

// pre = AGG/deg + b + Pr;  partial BN sums -> stats[0..127]=sum, stats[128..255]=sumsq
__global__ __launch_bounds__(128) void combine_kernel(const float* __restrict__ AGG,
                                                      const float* __restrict__ P,
                                                      const float* __restrict__ deg,
                                                      const float* __restrict__ bias,
                                                      float* __restrict__ Hpre,
                                                      float* __restrict__ stats, int M)
{
    int c = threadIdx.x;
    float b = bias[c];
    float s = 0.f, s2 = 0.f;
    int n0 = blockIdx.x * 128;
    for (int rr = 0; rr < 128; rr++) {
        int n = n0 + rr;
        if (n >= M) break;
        float inv = 1.0f / fmaxf(deg[n], 1.0f);
        float pre = AGG[(size_t)n * HIDC + c] * inv + b + P[(size_t)n * 256 + HIDC + c];
        Hpre[(size_t)n * HIDC + c] = pre;
        s += pre; s2 += pre * pre;
    }
    atomicAdd(&stats[c], s);
    atomicAdd(&stats[HIDC + c], s2);
}

template<bool RELU, bool WRITE_F32>
__global__ void normalize_kernel(const float* __restrict__ Hpre, const float* __restrict__ stats,
                                 const float* __restrict__ g, const float* __restrict__ be,
                                 bf16_t* __restrict__ Hb, float* __restrict__ Hf, int M)
{
    int i = blockIdx.x * blockDim.x + threadIdx.x;
    if (i >= M * HIDC) return;
    int c = i & 127;
    float invM  = 1.0f / (float)M;
    float mean  = stats[c] * invM;
    float var   = stats[HIDC + c] * invM - mean * mean;
    float scale = rsqrtf(var + BN_EPSC) * g[c];
    float v = (Hpre[i] - mean) * scale + be[c];
    if (RELU) v = fmaxf(v, 0.0f);
    Hb[i] = (bf16_t)v;
    if (WRITE_F32) Hf[i] = v;
}

__global__ __launch_bounds__(128) void pool_kernel(const float* __restrict__ H,
                                                   const int* __restrict__ batch,
                                                   float* __restrict__ pooled, int M)
{
    int gph = blockIdx.x;
    int c   = threadIdx.x;
    int lo = 0, hi = M;
    while (lo < hi) { int m = (lo + hi) >> 1; if (batch[m] < gph) lo = m + 1; else hi = m; }
    int lo2 = lo, hi2 = M;
    while (lo2 < hi2) { int m = (lo2 + hi2) >> 1; if (batch[m] < gph + 1) lo2 = m + 1; else hi2 = m; }
    float mx = -INFINITY;
    for (int rr = lo; rr < lo2; rr++) mx = fmaxf(mx, H[(size_t)rr * HIDC + c]);
    pooled[gph * HIDC + c] = mx;
}

__global__ __launch_bounds__(128) void final_kernel(const float* __restrict__ pooled,
                                                    const float* __restrict__ W,
                                                    const float* __restrict__ bl,
                                                    float* __restrict__ out)
{
    __shared__ float sp[HIDC];
    int gph = blockIdx.x;
    int t   = threadIdx.x;
    sp[t] = pooled[gph * HIDC + t];
    __syncthreads();
    if (t < NCLSC) {
        float acc = bl[t];
        for (int c = 0; c < HIDC; c++) acc += sp[c] * W[t * HIDC + c];
        out[gph * NCLSC + t] = acc;
    }
}

extern "C" void kernel_launch(void* const* d_in, const int* in_sizes, int n_in,
                              void* d_out, int out_size, void* d_ws, size_t ws_size,
                              hipStream_t stream)
{
    const float* x     = (const float*)d_in[0];
    const int*   ei    = (const int*)d_in[1];
    const int*   batch = (const int*)d_in[2];
    const float* W1l = (const float*)d_in[3];
    const float* b1  = (const float*)d_in[4];
    const float* W1r = (const float*)d_in[5];
    const float* g1  = (const float*)d_in[6];
    const float* be1 = (const float*)d_in[7];
    const float* W2l = (const float*)d_in[8];
    const float* b2  = (const float*)d_in[9];
    const float* W2r = (const float*)d_in[10];
    const float* g2  = (const float*)d_in[11];
    const float* be2 = (const float*)d_in[12];
    const float* W3l = (const float*)d_in[13];
    const float* b3  = (const float*)d_in[14];
    const float* W3r = (const float*)d_in[15];
    const float* g3  = (const float*)d_in[16];
    const float* be3 = (const float*)d_in[17];
    const float* Wlin = (const float*)d_in[18];
    const float* blin = (const float*)d_in[19];

    const int M = N_NODESC;

    // workspace carve (sizes in bytes, 256B-aligned naturally)
    char* w = (char*)d_ws;
    float*  P      = (float*)w;              w += (size_t)M * 256 * 4;   // 51.2 MB
    float*  AGG    = (float*)w;              w += (size_t)M * HIDC * 4;  // 25.6 MB
    float*  Hpre   = (float*)w;              w += (size_t)M * HIDC * 4;  // 25.6 MB
    bf16_t* Hb     = (bf16_t*)w;             w += (size_t)M * HIDC * 2;  // 12.8 MB
    float*  deg    = (float*)w;              w += (size_t)M * 4;
    float*  stats  = (float*)w;              w += 256 * 4;
    float*  pooled = (float*)w;              w += (size_t)N_GRAPHSC * HIDC * 4;
    float*  H3     = P;                      // reuse: P dead after layer-3 combine

    const dim3 gemm_grid((M + 127) / 128, 2);
    const int scat_blocks = (N_EDGESC * HIDC + 255) / 256;
    const int norm_blocks = (M * HIDC + 255) / 256;
    const int comb_blocks = (M + 127) / 128;

    hipMemsetAsync(deg, 0, (size_t)M * 4, stream);
    deg_kernel<<<(N_EDGESC + 255) / 256, 256, 0, stream>>>(ei, deg);

    // ---- layer 1 (K = 768, A = x fp32) ----
    gemm_kernel<true><<<gemm_grid, 256, 0, stream>>>(x, W1l, W1r, P, M, IN_DIMC);
    hipMemsetAsync(AGG, 0, (size_t)M * HIDC * 4, stream);
    hipMemsetAsync(stats, 0, 256 * 4, stream);
    scatter_kernel<<<scat_blocks, 256, 0, stream>>>(ei, P, AGG);
    combine_kernel<<<comb_blocks, 128, 0, stream>>>(AGG, P, deg, b1, Hpre, stats, M);
    normalize_kernel<true, false><<<norm_blocks, 256, 0, stream>>>(Hpre, stats, g1, be1, Hb, nullptr, M);

    // ---- layer 2 (K = 128, A = Hb bf16) ----
    gemm_kernel<false><<<gemm_grid, 256, 0, stream>>>(Hb, W2l, W2r, P, M, HIDC);
    hipMemsetAsync(AGG, 0, (size_t)M * HIDC * 4, stream);
    hipMemsetAsync(stats, 0, 256 * 4, stream);
    scatter_kernel<<<scat_blocks, 256, 0, stream>>>(ei, P, AGG);
    combine_kernel<<<comb_blocks, 128, 0, stream>>>(AGG, P, deg, b2, Hpre, stats, M);
    normalize_kernel<true, false><<<norm_blocks, 256, 0, stream>>>(Hpre, stats, g2, be2, Hb, nullptr, M);

    // ---- layer 3 (K = 128, no ReLU, need fp32 output for pooling) ----
    gemm_kernel<false><<<gemm_grid, 256, 0, stream>>>(Hb, W3l, W3r, P, M, HIDC);
    hipMemsetAsync(AGG, 0, (size_t)M * HIDC * 4, stream);
    hipMemsetAsync(stats, 0, 256 * 4, stream);
    scatter_kernel<<<scat_blocks, 256, 0, stream>>>(ei, P, AGG);
    combine_kernel<<<comb_blocks, 128, 0, stream>>>(AGG, P, deg, b3, Hpre, stats, M);
    normalize_kernel<false, true><<<norm_blocks, 256, 0, stream>>>(Hpre, stats, g3, be3, Hb, H3, M);

    // ---- pool + head ----
    pool_kernel<<<N_GRAPHSC, 128, 0, stream>>>(H3, batch, pooled, M);
    final_kernel<<<N_GRAPHSC, 128, 0, stream>>>(pooled, Wlin, blin, (float*)d_out);
}